// Round 17
// baseline (29.212 us; speedup 1.0000x reference)
//
#include <hip/hip_runtime.h>

// BipartPool fused: GATv2 bipartite pooling, fully-regular structure.
// lrelu(z) = 0.6z + 0.4|z| -> logit = 0.6*dot(xl,att) + s_r(r,h) + sum_c |xl+xr|*0.4att
// No-max softmax (logits ~N(0,1), f32 exp safe): alpha = ex/den; den divided out in k2;
// PV runs on unnormalized ex; den comes free as a ones-column MFMA.
// R16->R17 (occupancy experiment, last standing hypothesis: k1 is LATENCY-bound at
// 2 blocks/CU): LDS 62.7->49.4 KB => 3 blocks/CU (12 waves/CU, +50%).
//   (1) stride-72 pad -> stride-64 + XOR-swizzle on 16B units (R8-proven addressing)
//   (2) XR table f32 16KB -> packed bf16 pairs 8KB (R15-proven; its ~2us VALU cost is
//       the price of the 3rd resident block)
// All 4 TBAA barriers kept; n-indexed bf16 packs stay manual f2bf (R9 lesson).

typedef __attribute__((ext_vector_type(8))) short short8;
typedef __attribute__((ext_vector_type(4))) float f32x4;

#define NPG 1024
#define NT 512

static __device__ __forceinline__ unsigned short f2bf(float f) {
    unsigned int u = __float_as_uint(f);
    u += 0x7fffu + ((u >> 16) & 1u);        // RNE (data is normal, no NaN handling)
    return (unsigned short)(u >> 16);
}
static __device__ __forceinline__ float bf2f(unsigned short u) {
    return __uint_as_float(((unsigned int)u) << 16);
}
// packed f32->bf16 pair (k-indexed pairs ONLY; orientation-swap must be invariant)
static __device__ __forceinline__ unsigned int cvt2(float a, float b) {
    unsigned int r;
    asm("v_cvt_pk_bf16_f32 %0, %1, %2" : "=v"(r) : "v"(a), "v"(b));
    return r;
}
// swizzled column (shorts): unit = 8 shorts (16B); involution unit ^= row&7 (R8-proven)
static __device__ __forceinline__ int swz(int row, int unit) { return (unit ^ (row & 7)) << 3; }

// ---------------- K1: tables (fused k0) -> xl -> logits -> ex -> PV bf16 partials --------
__global__ __launch_bounds__(256, 2) void k1_fused(const float* __restrict__ x,
                                                   const float* __restrict__ W_l,
                                                   const float* __restrict__ W_r,
                                                   const float* __restrict__ b_l,
                                                   const float* __restrict__ b_r,
                                                   const float* __restrict__ xcb,
                                                   const float* __restrict__ att,
                                                   unsigned short* __restrict__ ws_pvh,
                                                   float* __restrict__ ws_denp) {
    // LL rows 0..63 = staged x (aliases xlT head 0); rows 0..255 = xlT[hc][n];
    // rows 256..319 = exT[h*16+r][n] (rows 256..271 alias XCB staging until B ends).
    // Stride 64 shorts, XOR-swizzled 16B units. 40960 B.
    __shared__ __align__(16) short LL[320][64];
    __shared__ __align__(16) unsigned int XR4b[256][8];   // xr bf16 pairs, 8192 B
    __shared__ float SS[64];                              // s_r as [h*16+r]

    const int t = threadIdx.x;
    const int blk = blockIdx.x;              // 512 tiles of 64 nodes
    const int n0 = blk * 64;

    // ---- phase A: stage x[64n][64k] f32 -> bf16 LL rows 0..63; stage xcb -> rows 256+ ----
    {
        int n = t >> 2, u0 = (t & 3) * 2;    // 4 threads/node, 2 units (16 shorts) each
        const float* p = x + (size_t)(n0 + n) * 64 + u0 * 8;
        float4 v0 = *(const float4*)p;
        float4 v1 = *(const float4*)(p + 4);
        float4 v2 = *(const float4*)(p + 8);
        float4 v3 = *(const float4*)(p + 12);
        uint4 a, b;
        a.x = cvt2(v0.x, v0.y); a.y = cvt2(v0.z, v0.w);
        a.z = cvt2(v1.x, v1.y); a.w = cvt2(v1.z, v1.w);
        b.x = cvt2(v2.x, v2.y); b.y = cvt2(v2.z, v2.w);
        b.z = cvt2(v3.x, v3.y); b.w = cvt2(v3.z, v3.w);
        *(uint4*)(&LL[n][swz(n, u0)])     = a;   // barrier 1 fences type-pun vs reads
        *(uint4*)(&LL[n][swz(n, u0 + 1)]) = b;
        // xcb tile: thread t -> row 256+(t>>4), k quad (t&15)*4 (uint2 within one unit)
        int rr = 256 + (t >> 4), k4 = (t & 15) * 4;
        float4 cv = *(const float4*)(xcb + (t >> 4) * 64 + k4);
        uint2 cw; cw.x = cvt2(cv.x, cv.y); cw.y = cvt2(cv.z, cv.w);
        *(uint2*)(&LL[rr][swz(rr, k4 >> 3) + (k4 & 7)]) = cw;
    }
    __syncthreads();                         // barrier 1: staged tiles visible

    const int l = t & 63;
    const int h = __builtin_amdgcn_readfirstlane(t >> 6);   // wave = head
    const int lm = l & 15, lq = l >> 4;
    const int lk = lq * 8;

    // ---- phase B: B-frags from raw W_l/W_r (scattered dwords, L2-hot) + MFMAs ----
    short8 af[4][2], bfr[4][2], brf[4][2];
#pragma unroll
    for (int nt = 0; nt < 4; ++nt)
#pragma unroll
        for (int ks = 0; ks < 2; ++ks) {
            const float* wl = W_l + (size_t)(ks * 32 + lk) * 256 + h * 64 + nt * 16 + lm;
            const float* wr = W_r + (size_t)(ks * 32 + lk) * 256 + h * 64 + nt * 16 + lm;
            uint4 pl, pr;
            pl.x = cvt2(wl[0 * 256], wl[1 * 256]); pl.y = cvt2(wl[2 * 256], wl[3 * 256]);
            pl.z = cvt2(wl[4 * 256], wl[5 * 256]); pl.w = cvt2(wl[6 * 256], wl[7 * 256]);
            pr.x = cvt2(wr[0 * 256], wr[1 * 256]); pr.y = cvt2(wr[2 * 256], wr[3 * 256]);
            pr.z = cvt2(wr[4 * 256], wr[5 * 256]); pr.w = cvt2(wr[6 * 256], wr[7 * 256]);
            bfr[nt][ks] = *(short8*)&pl;
            brf[nt][ks] = *(short8*)&pr;
        }
#pragma unroll
    for (int mt = 0; mt < 4; ++mt)
#pragma unroll
        for (int ks = 0; ks < 2; ++ks) {
            int row = mt * 16 + lm;
            af[mt][ks] = *(const short8*)(&LL[row][swz(row, ks * 4 + lq)]);
        }
    short8 axc[2];
#pragma unroll
    for (int ks = 0; ks < 2; ++ks) {
        int row = 256 + lm;
        axc[ks] = *(const short8*)(&LL[row][swz(row, ks * 4 + lq)]);
    }

    f32x4 acc[4][4], axr[4];
#pragma unroll
    for (int mt = 0; mt < 4; ++mt)
#pragma unroll
        for (int nt = 0; nt < 4; ++nt) { f32x4 z = {0.f,0.f,0.f,0.f}; acc[mt][nt] = z; }
#pragma unroll
    for (int nt = 0; nt < 4; ++nt) { f32x4 z = {0.f,0.f,0.f,0.f}; axr[nt] = z; }
#pragma unroll
    for (int mt = 0; mt < 4; ++mt)
#pragma unroll
        for (int nt = 0; nt < 4; ++nt)
#pragma unroll
            for (int ks = 0; ks < 2; ++ks)
                acc[mt][nt] = __builtin_amdgcn_mfma_f32_16x16x32_bf16(
                    af[mt][ks], bfr[nt][ks], acc[mt][nt], 0, 0, 0);
#pragma unroll
    for (int nt = 0; nt < 4; ++nt)
#pragma unroll
        for (int ks = 0; ks < 2; ++ks)
            axr[nt] = __builtin_amdgcn_mfma_f32_16x16x32_bf16(
                axc[ks], brf[nt][ks], axr[nt], 0, 0, 0);   // xr = xcb @ W_r (head h)

    __syncthreads();   // barrier 2: all frag reads done; xlT may overwrite staged rows

    // ---- phase C: acc(+b_l) -> xlT rows h*64.. bf16 (manual f2bf: n-pairs!) ----
    // C layout: col(c) = lm (+nt*16), row(n) = lq*4 + j (+mt*16)   [m89-verified]
#pragma unroll
    for (int nt = 0; nt < 4; ++nt) {
        float bl = b_l[h * 64 + nt * 16 + lm];
#pragma unroll
        for (int mt = 0; mt < 4; ++mt) {
            unsigned int d0 = (unsigned int)f2bf(acc[mt][nt][0] + bl) |
                              ((unsigned int)f2bf(acc[mt][nt][1] + bl) << 16);
            unsigned int d1 = (unsigned int)f2bf(acc[mt][nt][2] + bl) |
                              ((unsigned int)f2bf(acc[mt][nt][3] + bl) << 16);
            int row = h * 64 + nt * 16 + lm;
            int ncol = mt * 16 + lq * 4;                  // 4-short aligned
            *(uint2*)(&LL[row][swz(row, ncol >> 3) + (ncol & 7)]) = make_uint2(d0, d1);
        }
    }
    // xr(+b_r) -> XR4b[hc][8 bf16-pairs]; s_r partials from f32 frags, shfl-reduce over lm
    {
        float brv[4], atw[4], pj[4];
#pragma unroll
        for (int nt = 0; nt < 4; ++nt) {
            brv[nt] = b_r[h * 64 + nt * 16 + lm];
            atw[nt] = att[h * 64 + nt * 16 + lm];
        }
#pragma unroll
        for (int j = 0; j < 4; ++j) pj[j] = 0.f;
#pragma unroll
        for (int nt = 0; nt < 4; ++nt) {
            float4 w;
            w.x = axr[nt][0] + brv[nt]; w.y = axr[nt][1] + brv[nt];
            w.z = axr[nt][2] + brv[nt]; w.w = axr[nt][3] + brv[nt];
            unsigned int p0 = (unsigned int)f2bf(w.x) | ((unsigned int)f2bf(w.y) << 16);
            unsigned int p1 = (unsigned int)f2bf(w.z) | ((unsigned int)f2bf(w.w) << 16);
            *(uint2*)(&XR4b[h * 64 + nt * 16 + lm][lq * 2]) = make_uint2(p0, p1);
            pj[0] = fmaf(w.x, atw[nt], pj[0]); pj[1] = fmaf(w.y, atw[nt], pj[1]);
            pj[2] = fmaf(w.z, atw[nt], pj[2]); pj[3] = fmaf(w.w, atw[nt], pj[3]);
        }
#pragma unroll
        for (int j = 0; j < 4; ++j) {
            pj[j] += __shfl_xor(pj[j], 1); pj[j] += __shfl_xor(pj[j], 2);
            pj[j] += __shfl_xor(pj[j], 4); pj[j] += __shfl_xor(pj[j], 8);
        }
        if (lm == 0) {
#pragma unroll
            for (int j = 0; j < 4; ++j) SS[h * 16 + lq * 4 + j] = 0.6f * pj[j];
        }
    }
    __syncthreads();   // barrier 3: fence uint2 stores vs phase-D reads (TBAA)

    // ---- phase D: logits; xr rows = 2x b128 broadcast (bf16 pairs), unpack in VALU ----
    float base = 0.f;
    float lacc[16];
#pragma unroll
    for (int r = 0; r < 16; ++r) lacc[r] = 0.f;
#pragma unroll 4
    for (int c = 0; c < 64; ++c) {
        int row = h * 64 + c;
        float xv = bf2f((unsigned short)LL[row][swz(row, l >> 3) + (l & 7)]);
        float attv = att[row];                                // wave-uniform s_load
        base = fmaf(xv, attv, base);
        float a4 = 0.4f * attv;
        const uint4* xp = (const uint4*)(&XR4b[row][0]);      // wave-uniform -> broadcast
        uint4 w0 = xp[0], w1 = xp[1];
        float xr4v[16];
        xr4v[0]  = __uint_as_float(w0.x << 16); xr4v[1]  = __uint_as_float(w0.x & 0xffff0000u);
        xr4v[2]  = __uint_as_float(w0.y << 16); xr4v[3]  = __uint_as_float(w0.y & 0xffff0000u);
        xr4v[4]  = __uint_as_float(w0.z << 16); xr4v[5]  = __uint_as_float(w0.z & 0xffff0000u);
        xr4v[6]  = __uint_as_float(w0.w << 16); xr4v[7]  = __uint_as_float(w0.w & 0xffff0000u);
        xr4v[8]  = __uint_as_float(w1.x << 16); xr4v[9]  = __uint_as_float(w1.x & 0xffff0000u);
        xr4v[10] = __uint_as_float(w1.y << 16); xr4v[11] = __uint_as_float(w1.y & 0xffff0000u);
        xr4v[12] = __uint_as_float(w1.z << 16); xr4v[13] = __uint_as_float(w1.z & 0xffff0000u);
        xr4v[14] = __uint_as_float(w1.w << 16); xr4v[15] = __uint_as_float(w1.w & 0xffff0000u);
#pragma unroll
        for (int r = 0; r < 16; ++r)
            lacc[r] = fmaf(fabsf(xv + xr4v[r]), a4, lacc[r]); // abs = free VOP3 modifier
    }
    base *= 0.6f;
#pragma unroll
    for (int r = 0; r < 16; ++r) {
        float ex = __expf(base + lacc[r] + SS[h * 16 + r]);   // no-max softmax
        int row = 256 + h * 16 + r;
        LL[row][swz(row, l >> 3) + (l & 7)] = (short)f2bf(ex);
    }
    __syncthreads();   // barrier 4: fence E scalar stores vs phase-E short8 reads

    // ---- phase E: PV MFMA: pacc[16r][64c] = ex^T @ xl ; ones-col B gives den ----
    short8 ap[2];
#pragma unroll
    for (int ks = 0; ks < 2; ++ks) {
        int row = 256 + h * 16 + lm;
        ap[ks] = *(const short8*)(&LL[row][swz(row, ks * 4 + lq)]);
    }
    short o = (lm == 0) ? (short)0x3F80 : (short)0;   // bf16 1.0 in column 0
    short8 onesf = {o, o, o, o, o, o, o, o};

    f32x4 pacc[4], dacc;
    { f32x4 z = {0.f,0.f,0.f,0.f}; pacc[0]=z; pacc[1]=z; pacc[2]=z; pacc[3]=z; dacc=z; }
#pragma unroll
    for (int ks = 0; ks < 2; ++ks) {
#pragma unroll
        for (int nt = 0; nt < 4; ++nt) {
            int row = h * 64 + nt * 16 + lm;
            short8 bp = *(const short8*)(&LL[row][swz(row, ks * 4 + lq)]);
            pacc[nt] = __builtin_amdgcn_mfma_f32_16x16x32_bf16(ap[ks], bp, pacc[nt], 0, 0, 0);
        }
        dacc = __builtin_amdgcn_mfma_f32_16x16x32_bf16(ap[ks], onesf, dacc, 0, 0, 0);
    }

    // ---- store partials: pvh[blk][h][16r][64c] bf16, denp[blk][h][16r] f32 ----
    unsigned short* pvb = ws_pvh + ((size_t)blk * 4 + h) * 1024;
#pragma unroll
    for (int nt = 0; nt < 4; ++nt)
#pragma unroll
        for (int j = 0; j < 4; ++j)
            pvb[(lq * 4 + j) * 64 + nt * 16 + lm] = f2bf(pacc[nt][j]);
    if (lm == 0) {
#pragma unroll
        for (int j = 0; j < 4; ++j)
            ws_denp[((size_t)blk * 4 + h) * 16 + lq * 4 + j] = dacc[j];
    }
}

// ---------------- K2: 512 blocks: one (g,r) each; wave = head; LDS combine --------------
__global__ __launch_bounds__(256) void k2_final(const unsigned short* __restrict__ ws_pvh,
                                                const float* __restrict__ ws_denp,
                                                const float* __restrict__ bias,
                                                float* __restrict__ out) {
    __shared__ float sm[4][64];
    int b = blockIdx.x;                         // 512 main + 2 batchcent blocks
    if (b < 512) {
        int g = b >> 4, r = b & 15;
        int c = threadIdx.x & 63, hw = threadIdx.x >> 6;   // wave = head
        float num = 0.f, den = 0.f;
#pragma unroll
        for (int tl = 0; tl < 16; ++tl) {
            num += bf2f(ws_pvh[(((size_t)(g * 16 + tl) * 4 + hw) * 16 + r) * 64 + c]);
            den += ws_denp[((size_t)(g * 16 + tl) * 4 + hw) * 16 + r];   // s_loads
        }
        sm[hw][c] = num / den;
        __syncthreads();
        if (threadIdx.x < 64) {
            float s = (sm[0][c] + sm[1][c]) + (sm[2][c] + sm[3][c]);
            out[(size_t)(g * 16 + r) * 64 + c] = fmaf(0.25f, s, bias[c]);
        }
    } else {
        int tt = (b - 512) * 256 + threadIdx.x;     // batchcent (input-independent)
        out[NT * 64 + tt] = (float)(tt >> 4);
    }
}

extern "C" void kernel_launch(void* const* d_in, const int* in_sizes, int n_in,
                              void* d_out, int out_size, void* d_ws, size_t ws_size,
                              hipStream_t stream) {
    const float* x    = (const float*)d_in[0];
    const float* xcb  = (const float*)d_in[3];
    const float* W_l  = (const float*)d_in[4];
    const float* b_l  = (const float*)d_in[5];
    const float* W_r  = (const float*)d_in[6];
    const float* b_r  = (const float*)d_in[7];
    const float* att  = (const float*)d_in[8];
    const float* bias = (const float*)d_in[9];
    float* out = (float*)d_out;

    // workspace layout (~4.3 MB)
    unsigned short* ws_pvh = (unsigned short*)d_ws;       // 512 blk x 4 h x 16 r x 64 c bf16
    float* ws_denp = (float*)(ws_pvh + 2097152);          // 512 x 4 x 16 f32

    k1_fused<<<512, 256, 0, stream>>>(x, W_l, W_r, b_l, b_r, xcb, att, ws_pvh, ws_denp);
    k2_final<<<514, 256, 0, stream>>>(ws_pvh, ws_denp, bias, out);
}

// Round 18
// 26.332 us; speedup vs baseline: 1.1094x; 1.1094x over previous
//
#include <hip/hip_runtime.h>

// BipartPool fused: GATv2 bipartite pooling, fully-regular structure.
// lrelu(z) = 0.6z + 0.4|z| -> logit = 0.6*dot(xl,att) + s_r(r,h) + sum_c |xl+xr|*0.4att
// No-max softmax (logits ~N(0,1), f32 exp safe): alpha = ex/den; den divided out in k2;
// PV runs on unnormalized ex; den comes free as a ones-column MFMA.
// FINAL = R16 config (26.36us, absmax 1e-3), restored after R17's occupancy experiment
// regressed (29.2us: 3-blocks/CU via swizzle+packed-XR didn't pay for packed-XR's VALU
// cost). Dead theories, each tested in isolation: phase-D SMEM stall (R12 neutral),
// LDS-pipe bound (R15 regressed), 8-wave split (R8 regressed), occupancy (R17 regressed).
// Surviving model: k1 at a composite issue/dep-chain floor; k2 at 2 blk/CU latency-fixed.

typedef __attribute__((ext_vector_type(8))) short short8;
typedef __attribute__((ext_vector_type(4))) float f32x4;

#define NPG 1024
#define NT 512

static __device__ __forceinline__ unsigned short f2bf(float f) {
    unsigned int u = __float_as_uint(f);
    u += 0x7fffu + ((u >> 16) & 1u);        // RNE (data is normal, no NaN handling)
    return (unsigned short)(u >> 16);
}
static __device__ __forceinline__ float bf2f(unsigned short u) {
    return __uint_as_float(((unsigned int)u) << 16);
}
// packed f32->bf16 pair (k-indexed pairs ONLY; orientation-swap must be invariant)
static __device__ __forceinline__ unsigned int cvt2(float a, float b) {
    unsigned int r;
    asm("v_cvt_pk_bf16_f32 %0, %1, %2" : "=v"(r) : "v"(a), "v"(b));
    return r;
}

// ---------------- K1: tables (fused k0) -> xl -> logits -> ex -> PV bf16 partials --------
__global__ __launch_bounds__(256, 2) void k1_fused(const float* __restrict__ x,
                                                   const float* __restrict__ W_l,
                                                   const float* __restrict__ W_r,
                                                   const float* __restrict__ b_l,
                                                   const float* __restrict__ b_r,
                                                   const float* __restrict__ xcb,
                                                   const float* __restrict__ att,
                                                   unsigned short* __restrict__ ws_pvh,
                                                   float* __restrict__ ws_denp) {
    __shared__ __align__(16) unsigned char smraw[(256 + 64) * 72 * 2];   // 46080 B
    __shared__ __align__(16) float XR4[256][16];                         // 16384 B
    __shared__ float SS[64];                                             // s_r as [h*16+r]
    unsigned short (*As)[72]  = (unsigned short (*)[72])smraw;           // 64x72 (aliases xlT)
    unsigned short (*xlT)[72] = (unsigned short (*)[72])smraw;           // [h*64+c][n]
    unsigned short (*exT)[72] = (unsigned short (*)[72])(smraw + 256 * 72 * 2); // [h*16+r][n]
    unsigned short (*XCB)[72] = exT;   // rows 0..15 reused as xcb tile until phase B ends

    const int t = threadIdx.x;
    const int blk = blockIdx.x;              // 512 tiles of 64 nodes
    const int n0 = blk * 64;

    // ---- phase A: stage x[64n][64k] f32 -> bf16 As; stage xcb[16][64k] -> XCB ----
    {
        int n = t >> 2, q = (t & 3) * 16;
        const float* p = x + (size_t)(n0 + n) * 64 + q;
        float4 v0 = *(const float4*)p;
        float4 v1 = *(const float4*)(p + 4);
        float4 v2 = *(const float4*)(p + 8);
        float4 v3 = *(const float4*)(p + 12);
        uint4 a, b;
        a.x = cvt2(v0.x, v0.y); a.y = cvt2(v0.z, v0.w);
        a.z = cvt2(v1.x, v1.y); a.w = cvt2(v1.z, v1.w);
        b.x = cvt2(v2.x, v2.y); b.y = cvt2(v2.z, v2.w);
        b.z = cvt2(v3.x, v3.y); b.w = cvt2(v3.z, v3.w);
        *(uint4*)(&As[n][q])     = a;        // barrier 1 fences type-pun vs short8 reads
        *(uint4*)(&As[n][q + 8]) = b;
        // xcb tile: thread t -> row t>>4 (0..15), k quad (t&15)*4
        int rr = t >> 4, k4 = (t & 15) * 4;
        float4 cv = *(const float4*)(xcb + rr * 64 + k4);
        uint2 cw; cw.x = cvt2(cv.x, cv.y); cw.y = cvt2(cv.z, cv.w);
        *(uint2*)(&XCB[rr][k4]) = cw;
    }
    __syncthreads();                         // barrier 1: staged tiles visible

    const int l = t & 63;
    const int h = __builtin_amdgcn_readfirstlane(t >> 6);   // wave = head
    const int lm = l & 15, lq = l >> 4;
    const int lk = lq * 8;

    // ---- phase B: B-frags from raw W_l/W_r (scattered dwords, L2-hot) + MFMAs ----
    short8 af[4][2], bfr[4][2], brf[4][2];
#pragma unroll
    for (int nt = 0; nt < 4; ++nt)
#pragma unroll
        for (int ks = 0; ks < 2; ++ks) {
            const float* wl = W_l + (size_t)(ks * 32 + lk) * 256 + h * 64 + nt * 16 + lm;
            const float* wr = W_r + (size_t)(ks * 32 + lk) * 256 + h * 64 + nt * 16 + lm;
            uint4 pl, pr;
            pl.x = cvt2(wl[0 * 256], wl[1 * 256]); pl.y = cvt2(wl[2 * 256], wl[3 * 256]);
            pl.z = cvt2(wl[4 * 256], wl[5 * 256]); pl.w = cvt2(wl[6 * 256], wl[7 * 256]);
            pr.x = cvt2(wr[0 * 256], wr[1 * 256]); pr.y = cvt2(wr[2 * 256], wr[3 * 256]);
            pr.z = cvt2(wr[4 * 256], wr[5 * 256]); pr.w = cvt2(wr[6 * 256], wr[7 * 256]);
            bfr[nt][ks] = *(short8*)&pl;
            brf[nt][ks] = *(short8*)&pr;
        }
#pragma unroll
    for (int mt = 0; mt < 4; ++mt)
#pragma unroll
        for (int ks = 0; ks < 2; ++ks)
            af[mt][ks] = *(const short8*)(&As[mt * 16 + lm][ks * 32 + lk]);
    short8 axc[2];
#pragma unroll
    for (int ks = 0; ks < 2; ++ks)
        axc[ks] = *(const short8*)(&XCB[lm][ks * 32 + lk]);

    f32x4 acc[4][4], axr[4];
#pragma unroll
    for (int mt = 0; mt < 4; ++mt)
#pragma unroll
        for (int nt = 0; nt < 4; ++nt) { f32x4 z = {0.f,0.f,0.f,0.f}; acc[mt][nt] = z; }
#pragma unroll
    for (int nt = 0; nt < 4; ++nt) { f32x4 z = {0.f,0.f,0.f,0.f}; axr[nt] = z; }
#pragma unroll
    for (int mt = 0; mt < 4; ++mt)
#pragma unroll
        for (int nt = 0; nt < 4; ++nt)
#pragma unroll
            for (int ks = 0; ks < 2; ++ks)
                acc[mt][nt] = __builtin_amdgcn_mfma_f32_16x16x32_bf16(
                    af[mt][ks], bfr[nt][ks], acc[mt][nt], 0, 0, 0);
#pragma unroll
    for (int nt = 0; nt < 4; ++nt)
#pragma unroll
        for (int ks = 0; ks < 2; ++ks)
            axr[nt] = __builtin_amdgcn_mfma_f32_16x16x32_bf16(
                axc[ks], brf[nt][ks], axr[nt], 0, 0, 0);   // xr = xcb @ W_r (head h)

    __syncthreads();   // barrier 2: all frag reads done; xlT may overwrite As/XCB

    // ---- phase C: acc(+b_l) -> xlT[h*64+c][n] bf16 (manual f2bf: n-pairs!) ----
    // C layout: col(c) = lm (+nt*16), row(n) = lq*4 + j (+mt*16)   [m89-verified]
#pragma unroll
    for (int nt = 0; nt < 4; ++nt) {
        float bl = b_l[h * 64 + nt * 16 + lm];
#pragma unroll
        for (int mt = 0; mt < 4; ++mt) {
            unsigned int d0 = (unsigned int)f2bf(acc[mt][nt][0] + bl) |
                              ((unsigned int)f2bf(acc[mt][nt][1] + bl) << 16);
            unsigned int d1 = (unsigned int)f2bf(acc[mt][nt][2] + bl) |
                              ((unsigned int)f2bf(acc[mt][nt][3] + bl) << 16);
            *(uint2*)(&xlT[h * 64 + nt * 16 + lm][mt * 16 + lq * 4]) = make_uint2(d0, d1);
        }
    }
    // xr(+b_r) -> XR4[hc][16r]; s_r partials from frags, shfl-reduce over lm
    {
        float brv[4], atw[4], pj[4];
#pragma unroll
        for (int nt = 0; nt < 4; ++nt) {
            brv[nt] = b_r[h * 64 + nt * 16 + lm];
            atw[nt] = att[h * 64 + nt * 16 + lm];
        }
#pragma unroll
        for (int j = 0; j < 4; ++j) pj[j] = 0.f;
#pragma unroll
        for (int nt = 0; nt < 4; ++nt) {
            float4 w;
            w.x = axr[nt][0] + brv[nt]; w.y = axr[nt][1] + brv[nt];
            w.z = axr[nt][2] + brv[nt]; w.w = axr[nt][3] + brv[nt];
            *(float4*)(&XR4[h * 64 + nt * 16 + lm][lq * 4]) = w;
            pj[0] = fmaf(w.x, atw[nt], pj[0]); pj[1] = fmaf(w.y, atw[nt], pj[1]);
            pj[2] = fmaf(w.z, atw[nt], pj[2]); pj[3] = fmaf(w.w, atw[nt], pj[3]);
        }
#pragma unroll
        for (int j = 0; j < 4; ++j) {
            pj[j] += __shfl_xor(pj[j], 1); pj[j] += __shfl_xor(pj[j], 2);
            pj[j] += __shfl_xor(pj[j], 4); pj[j] += __shfl_xor(pj[j], 8);
        }
        if (lm == 0) {
#pragma unroll
            for (int j = 0; j < 4; ++j) SS[h * 16 + lq * 4 + j] = 0.6f * pj[j];
        }
    }
    __syncthreads();   // barrier 3: fence uint2/float4 stores vs phase-D reads (TBAA)

    // ---- phase D: logits; xr rows = LDS broadcast; att s_load scaled inline ----
    float base = 0.f;
    float lacc[16];
#pragma unroll
    for (int r = 0; r < 16; ++r) lacc[r] = 0.f;
#pragma unroll 4
    for (int c = 0; c < 64; ++c) {
        int row = h * 64 + c;
        float xv = bf2f(xlT[row][l]);
        float attv = att[row];                                // wave-uniform s_load
        base = fmaf(xv, attv, base);
        float a4 = 0.4f * attv;
        float xr4v[16];
        const float4* xp = (const float4*)(&XR4[row][0]);     // wave-uniform -> broadcast
        *(float4*)(xr4v + 0)  = xp[0];
        *(float4*)(xr4v + 4)  = xp[1];
        *(float4*)(xr4v + 8)  = xp[2];
        *(float4*)(xr4v + 12) = xp[3];
#pragma unroll
        for (int r = 0; r < 16; ++r)
            lacc[r] = fmaf(fabsf(xv + xr4v[r]), a4, lacc[r]); // abs = free VOP3 modifier
    }
    base *= 0.6f;
#pragma unroll
    for (int r = 0; r < 16; ++r) {
        float ex = __expf(base + lacc[r] + SS[h * 16 + r]);   // no-max softmax
        exT[h * 16 + r][l] = f2bf(ex);
    }
    __syncthreads();   // barrier 4: fence E scalar stores vs phase-E short8 reads

    // ---- phase E: PV MFMA: pacc[16r][64c] = ex^T @ xl ; ones-col B gives den ----
    short8 ap[2];
#pragma unroll
    for (int ks = 0; ks < 2; ++ks)
        ap[ks] = *(const short8*)(&exT[h * 16 + lm][ks * 32 + lk]);
    short o = (lm == 0) ? (short)0x3F80 : (short)0;   // bf16 1.0 in column 0
    short8 onesf = {o, o, o, o, o, o, o, o};

    f32x4 pacc[4], dacc;
    { f32x4 z = {0.f,0.f,0.f,0.f}; pacc[0]=z; pacc[1]=z; pacc[2]=z; pacc[3]=z; dacc=z; }
#pragma unroll
    for (int ks = 0; ks < 2; ++ks) {
#pragma unroll
        for (int nt = 0; nt < 4; ++nt) {
            short8 bp = *(const short8*)(&xlT[h * 64 + nt * 16 + lm][ks * 32 + lk]);
            pacc[nt] = __builtin_amdgcn_mfma_f32_16x16x32_bf16(ap[ks], bp, pacc[nt], 0, 0, 0);
        }
        dacc = __builtin_amdgcn_mfma_f32_16x16x32_bf16(ap[ks], onesf, dacc, 0, 0, 0);
    }

    // ---- store partials: pvh[blk][h][16r][64c] bf16, denp[blk][h][16r] f32 ----
    unsigned short* pvb = ws_pvh + ((size_t)blk * 4 + h) * 1024;
#pragma unroll
    for (int nt = 0; nt < 4; ++nt)
#pragma unroll
        for (int j = 0; j < 4; ++j)
            pvb[(lq * 4 + j) * 64 + nt * 16 + lm] = f2bf(pacc[nt][j]);
    if (lm == 0) {
#pragma unroll
        for (int j = 0; j < 4; ++j)
            ws_denp[((size_t)blk * 4 + h) * 16 + lq * 4 + j] = dacc[j];
    }
}

// ---------------- K2: 512 blocks: one (g,r) each; wave = head; LDS combine --------------
__global__ __launch_bounds__(256) void k2_final(const unsigned short* __restrict__ ws_pvh,
                                                const float* __restrict__ ws_denp,
                                                const float* __restrict__ bias,
                                                float* __restrict__ out) {
    __shared__ float sm[4][64];
    int b = blockIdx.x;                         // 512 main + 2 batchcent blocks
    if (b < 512) {
        int g = b >> 4, r = b & 15;
        int c = threadIdx.x & 63, hw = threadIdx.x >> 6;   // wave = head
        float num = 0.f, den = 0.f;
#pragma unroll
        for (int tl = 0; tl < 16; ++tl) {
            num += bf2f(ws_pvh[(((size_t)(g * 16 + tl) * 4 + hw) * 16 + r) * 64 + c]);
            den += ws_denp[((size_t)(g * 16 + tl) * 4 + hw) * 16 + r];   // s_loads
        }
        sm[hw][c] = num / den;
        __syncthreads();
        if (threadIdx.x < 64) {
            float s = (sm[0][c] + sm[1][c]) + (sm[2][c] + sm[3][c]);
            out[(size_t)(g * 16 + r) * 64 + c] = fmaf(0.25f, s, bias[c]);
        }
    } else {
        int tt = (b - 512) * 256 + threadIdx.x;     // batchcent (input-independent)
        out[NT * 64 + tt] = (float)(tt >> 4);
    }
}

extern "C" void kernel_launch(void* const* d_in, const int* in_sizes, int n_in,
                              void* d_out, int out_size, void* d_ws, size_t ws_size,
                              hipStream_t stream) {
    const float* x    = (const float*)d_in[0];
    const float* xcb  = (const float*)d_in[3];
    const float* W_l  = (const float*)d_in[4];
    const float* b_l  = (const float*)d_in[5];
    const float* W_r  = (const float*)d_in[6];
    const float* b_r  = (const float*)d_in[7];
    const float* att  = (const float*)d_in[8];
    const float* bias = (const float*)d_in[9];
    float* out = (float*)d_out;

    // workspace layout (~4.3 MB)
    unsigned short* ws_pvh = (unsigned short*)d_ws;       // 512 blk x 4 h x 16 r x 64 c bf16
    float* ws_denp = (float*)(ws_pvh + 2097152);          // 512 x 4 x 16 f32

    k1_fused<<<512, 256, 0, stream>>>(x, W_l, W_r, b_l, b_r, xcb, att, ws_pvh, ws_denp);
    k2_final<<<514, 256, 0, stream>>>(ws_pvh, ws_denp, bias, out);
}